// Round 9
// baseline (154.546 us; speedup 1.0000x reference)
//
#include <hip/hip_runtime.h>

#define B     64
#define CIN   3
#define COUT  16
#define H     256
#define W     256
#define HW    (H*W)
#define CHW   (CIN*H*W)
#define HO    255            // conv out spatial
#define WO    255
#define HF    254            // window out spatial
#define WF    254
#define NPIXF 4161600.0f     // B*HO*WO
#define BN_EPS 1e-5f
#define C2TANH 2.8853900817779268f   // 2*log2(e)

#define SEGS  32                     // 8-px segments per conv row
#define NITEM (B * HO * SEGS)        // 522,240 = 2040 * 256
#define STB   (NITEM / 256)          // 2040 blocks, one segment per thread
#define RCHUNK (STB / 8)             // 255 partial entries per reduce-thread

#define RB    7                      // output rows per fused block (8 s-rows)
#define RBLKS 37                     // ceil(HF/RB)
#define LSTR  260                    // LDS s-tile row stride

typedef float f2 __attribute__((ext_vector_type(2)));

__device__ __forceinline__ float4 ld4(const float* p) { return *(const float4*)p; }
__device__ __forceinline__ f2 pkfma(f2 a, f2 b, f2 c) { return __builtin_elementwise_fma(a, b, c); }
__device__ __forceinline__ f2 spl(float v) { return (f2){v, v}; }

// Load the patch as (u, u+4) pixel-pairs: per (row, ic) the 5 pairs
//   P[j] = (x_j, x_{j+4}), j=0..4   built from two float4 loads + 1 scalar.
// off8 clamps the 9th column in-bounds for the tail segment (masked/unused).
__device__ __forceinline__ void load_patch_pk(const float* xp, int off8,
                                              f2 X0[CIN][5], f2 X1[CIN][5]) {
#pragma unroll
    for (int ic = 0; ic < CIN; ic++) {
        const float* p0 = xp + ic * HW;
        const float* p1 = p0 + W;
        float4 a = ld4(p0), b = ld4(p0 + 4);
        float  e = p0[off8];
        X0[ic][0] = (f2){a.x, b.x}; X0[ic][1] = (f2){a.y, b.y};
        X0[ic][2] = (f2){a.z, b.z}; X0[ic][3] = (f2){a.w, b.w};
        X0[ic][4] = (f2){b.x, e};
        float4 c4 = ld4(p1), d = ld4(p1 + 4);
        float  e1 = p1[off8];
        X1[ic][0] = (f2){c4.x, d.x}; X1[ic][1] = (f2){c4.y, d.y};
        X1[ic][2] = (f2){c4.z, d.z}; X1[ic][3] = (f2){c4.w, d.w};
        X1[ic][4] = (f2){d.x, e1};
    }
}

// 12 packed FMAs: conv for pixel pair (k, k+4) of channel c.
// wq[0..11] are in-register f2 splats of the 12 scalar weights (op_sel-able).
#define CONV_PK(f, k)                                              \
    f = pkfma(wq0,  X0[0][k],   f);                                \
    f = pkfma(wq1,  X0[0][k+1], f);                                \
    f = pkfma(wq2,  X1[0][k],   f);                                \
    f = pkfma(wq3,  X1[0][k+1], f);                                \
    f = pkfma(wq4,  X0[1][k],   f);                                \
    f = pkfma(wq5,  X0[1][k+1], f);                                \
    f = pkfma(wq6,  X1[1][k],   f);                                \
    f = pkfma(wq7,  X1[1][k+1], f);                                \
    f = pkfma(wq8,  X0[2][k],   f);                                \
    f = pkfma(wq9,  X0[2][k+1], f);                                \
    f = pkfma(wq10, X1[2][k],   f);                                \
    f = pkfma(wq11, X1[2][k+1], f);

// Pull channel c's params from LDS as 4 x ds_read_b128 (R6's measured-good
// pattern: 64 LDS instrs/thread total) and splat to f2 in registers.
#define LOAD_WQ(c)                                                 \
    const float4* wv = (const float4*)(wpk + ((c) << 4));          \
    float4 wa = wv[0], wb = wv[1], wc4 = wv[2], wd = wv[3];        \
    f2 wq0 = spl(wa.x),  wq1 = spl(wa.y),  wq2 = spl(wa.z),        \
       wq3 = spl(wa.w),  wq4 = spl(wb.x),  wq5 = spl(wb.y),        \
       wq6 = spl(wb.z),  wq7 = spl(wb.w),  wq8 = spl(wc4.x),       \
       wq9 = spl(wc4.y), wq10 = spl(wc4.z), wq11 = spl(wc4.w);

// wpk layout per channel (16 floats): [0..11]=w, [12]=bias, [13]=scale2, [14]=shift2
template <bool WITH_BN>
__device__ __forceinline__ void load_wpk(float* wpk, const float* w,
                                         const float* bias, const float* gamma,
                                         const float* beta, const float* acc,
                                         int tid) {
    int c = tid >> 4, k = tid & 15;
    float v = 0.f;
    if (k < 12)       v = w[c * 12 + k];
    else if (k == 12) v = bias[c];
    else if (WITH_BN && k < 15) {
        float sv = acc[c], qv = acc[COUT + c];
        float mu  = sv * (1.f / NPIXF);
        float var = qv * (1.f / NPIXF) - mu * mu;
        float s   = gamma[c] * rsqrtf(var + BN_EPS);
        v = (k == 13) ? s * C2TANH : (beta[c] - mu * s) * C2TANH;
    }
    wpk[tid] = v;
}

// ---- kernel 1: per-channel sum/sumsq of conv+bias; one 8-px segment per thread.
//      Packed-f32 conv; LDS transpose reduce; per-block partials (no atomics).
__global__ __launch_bounds__(256) void k_stats(const float* __restrict__ x,
                                               const float* __restrict__ w,
                                               const float* __restrict__ bias,
                                               float* __restrict__ part) {
    __shared__ float wpk[COUT * 16];
    __shared__ float tr[256 * 33];   // [thread][c] stride 33 -> bank (tid+c)%32
    __shared__ float red2[8 * 33];
    int tid = threadIdx.x;
    load_wpk<false>(wpk, w, bias, nullptr, nullptr, nullptr, tid);
    __syncthreads();

    int item = blockIdx.x * 256 + tid;
    int jseg = item & (SEGS - 1);
    int row  = item >> 5;                 // b*HO + i
    int bb   = row / HO;
    int i    = row - bb * HO;
    const float* xp = x + (size_t)bb * CHW + i * W + (jseg << 3);
    bool tail = (jseg == SEGS - 1);
    int  off8 = tail ? 7 : 8;
    f2 mask3 = (f2){1.f, tail ? 0.f : 1.f};   // pixel 7 = pair3.y

    f2 X0[CIN][5], X1[CIN][5];
    load_patch_pk(xp, off8, X0, X1);

#pragma unroll
    for (int c = 0; c < COUT; c++) {
        LOAD_WQ(c)
        f2 bp = spl(wd.x);
        f2 sacc = spl(0.f), qacc = spl(0.f);
#pragma unroll
        for (int k = 0; k < 4; k++) {
            f2 f = bp;
            CONV_PK(f, k)
            if (k == 3) f *= mask3;
            sacc += f;
            qacc = pkfma(f, f, qacc);
        }
        tr[tid * 33 + c]        = sacc.x + sacc.y;
        tr[tid * 33 + COUT + c] = qacc.x + qacc.y;
    }
    __syncthreads();

    // column-chunk sums: thread (col=tid&31, chunk=tid>>5) sums 32 rows
    {
        int col = tid & 31, chunk = tid >> 5;
        int r0 = chunk << 5;
        float a0 = 0.f, a1 = 0.f, a2 = 0.f, a3 = 0.f;
#pragma unroll
        for (int k = 0; k < 32; k += 4) {
            a0 += tr[(r0 + k)     * 33 + col];
            a1 += tr[(r0 + k + 1) * 33 + col];
            a2 += tr[(r0 + k + 2) * 33 + col];
            a3 += tr[(r0 + k + 3) * 33 + col];
        }
        red2[chunk * 33 + col] = (a0 + a1) + (a2 + a3);
    }
    __syncthreads();
    if (tid < 32) {
        float s = 0.f;
#pragma unroll
        for (int k = 0; k < 8; k++) s += red2[k * 33 + tid];
        part[blockIdx.x * 32 + tid] = s;
    }
}

// ---- kernel 1b: fold 2040 x 32 partials -> acc[32] (one block, coalesced) ----
__global__ __launch_bounds__(256) void k_reduce(const float* __restrict__ part,
                                                float* __restrict__ acc) {
    __shared__ float red2[8 * 33];
    int tid = threadIdx.x;
    int col = tid & 31, chunk = tid >> 5;
    int base = chunk * RCHUNK;
    float a0 = 0.f, a1 = 0.f, a2 = 0.f, a3 = 0.f;
    int k = 0;
    for (; k + 3 < RCHUNK; k += 4) {
        a0 += part[(base + k)     * 32 + col];
        a1 += part[(base + k + 1) * 32 + col];
        a2 += part[(base + k + 2) * 32 + col];
        a3 += part[(base + k + 3) * 32 + col];
    }
    for (; k < RCHUNK; k++) a0 += part[(base + k) * 32 + col];
    red2[chunk * 33 + col] = (a0 + a1) + (a2 + a3);
    __syncthreads();
    if (tid < 32) {
        float s = 0.f;
#pragma unroll
        for (int j = 0; j < 8; j++) s += red2[j * 33 + tid];
        acc[tid] = s;
    }
}

// ---- kernel 2 (fused): BN finalize + s=sum_c tanh(relu(bn(conv))) tile + 2x2 window mean ----
__global__ __launch_bounds__(256) void k_csum(const float* __restrict__ x,
                                              const float* __restrict__ w,
                                              const float* __restrict__ bias,
                                              const float* __restrict__ gamma,
                                              const float* __restrict__ beta,
                                              const float* __restrict__ acc,
                                              float* __restrict__ out) {
    __shared__ float wpk[COUT * 16];
    __shared__ float sld[(RB + 1) * LSTR];
    int tid = threadIdx.x;
    load_wpk<true>(wpk, w, bias, gamma, beta, acc, tid);
    int blk   = blockIdx.x;
    int bb    = blk / RBLKS;
    int rblk  = blk - bb * RBLKS;
    int rbase = rblk * RB;
    __syncthreads();

    // phase 1: one 8-pixel s-segment per thread (8 rows x 32 segs = 256 tasks)
    int sr = tid >> 5;               // 0..7
    int si = rbase + sr;
    int jseg = tid & 31;
    int j0 = jseg << 3;
    if (si < HO) {
        const float* xp = x + (size_t)bb * CHW + si * W + j0;
        int off8 = (jseg == 31) ? 7 : 8;
        f2 X0[CIN][5], X1[CIN][5];
        load_patch_pk(xp, off8, X0, X1);

        f2 racc[4];
#pragma unroll
        for (int k = 0; k < 4; k++) racc[k] = spl(0.f);

#pragma unroll
        for (int c = 0; c < COUT; c++) {
            LOAD_WQ(c)
            f2 bp = spl(wd.x), s2 = spl(wd.y), h2 = spl(wd.z);
#pragma unroll
            for (int k = 0; k < 4; k++) {
                f2 f = bp;
                CONV_PK(f, k)
                f2 a2 = pkfma(s2, f, h2);                  // 2log2e*(scale*f+shift)
                a2 = __builtin_elementwise_max(a2, spl(0.f));  // relu (scaled)
                f2 E;
                E.x = __builtin_amdgcn_exp2f(a2.x);        // e^{2a}
                E.y = __builtin_amdgcn_exp2f(a2.y);
                E += spl(1.f);
                f2 r;
                r.x = __builtin_amdgcn_rcpf(E.x);
                r.y = __builtin_amdgcn_rcpf(E.y);
                racc[k] += r;                              // sum of 1/(e^{2a}+1)
            }
        }
        // s = COUT - 2*sum(r); pair k holds pixels (k, k+4)
        f2 sa[4];
#pragma unroll
        for (int k = 0; k < 4; k++) sa[k] = pkfma(spl(-2.f), racc[k], spl((float)COUT));
        float* sp = &sld[sr * LSTR + j0];
        *(float4*)sp       = make_float4(sa[0].x, sa[1].x, sa[2].x, sa[3].x);
        *(float4*)(sp + 4) = make_float4(sa[0].y, sa[1].y, sa[2].y, sa[3].y);
    }
    __syncthreads();

    // phase 2: 2x2 window means; thread -> (row tid>>5, cols (tid&31)+32u) coalesced
    int orl = tid >> 5;              // 0..7, valid rows 0..RB-1
    int orow = rbase + orl;
    if (orl < RB && orow < HF) {
        const float* s0 = &sld[orl * LSTR];
        const float* s1 = s0 + LSTR;
        float* op = out + ((size_t)bb * HF + orow) * WF;
        int oc0 = tid & 31;
#pragma unroll
        for (int u = 0; u < 8; u++) {
            int c = oc0 + (u << 5);
            if (c < WF) {
                op[c] = (s0[c] + s0[c+1] + s1[c] + s1[c+1]) * (1.f / (COUT * 4));
            }
        }
    }
}

extern "C" void kernel_launch(void* const* d_in, const int* in_sizes, int n_in,
                              void* d_out, int out_size, void* d_ws, size_t ws_size,
                              hipStream_t stream) {
    const float* x     = (const float*)d_in[0];
    const float* w     = (const float*)d_in[1];
    const float* bias  = (const float*)d_in[2];
    const float* gamma = (const float*)d_in[3];
    const float* beta  = (const float*)d_in[4];
    float* out = (float*)d_out;

    float* part = (float*)d_ws;          // STB*32 floats of per-block partials
    float* acc  = part + STB * 32;       // 32 floats: s[16], q[16]

    k_stats<<<STB, 256, 0, stream>>>(x, w, bias, part);
    k_reduce<<<1, 256, 0, stream>>>(part, acc);
    k_csum<<<B * RBLKS, 256, 0, stream>>>(x, w, bias, gamma, beta, acc, out);
}